// Round 5
// baseline (238.664 us; speedup 1.0000x reference)
//
#include <hip/hip_runtime.h>

// ShortConvolution: depthwise causal conv1d (K=4) + SiLU
// x: (B=4, T=4096, D=2048) fp32, weight: (D, K) fp32, out: (B, T, D) fp32
// y[b,t,d] = silu( sum_k w[d,k] * x[b, t-3+k, d] )   (x[t<0] = 0)
//
// R5: register-batched loads enforced by empty-asm value fences.
// R1/R2's batch was sunk row-by-row by the compiler (VGPR stayed 32/36 ->
// one round-trip in flight per wave -> 2.8 TB/s). R4's async-LDS also
// round-tripped per chunk at the barrier. Here each batch of 8 rows is
// loaded into registers and passed through asm volatile("" : "+v"(r)...):
// the values must exist in VGPRs at the fence, so the 8 global_load_dwordx4
// issue back-to-back with one graduated s_waitcnt -- the compiler cannot
// re-serialize. 16 waves/CU x ~11 KB in flight saturates memory under any
// latency model.

#define B_DIM  4
#define T_DIM  4096
#define D_DIM  2048
#define K_DIM  4
#define STRIP  32               // rows per block strip
#define U      8                // rows per batch
#define NCH    (T_DIM / STRIP)  // 128 strips along T

typedef float f4_t __attribute__((ext_vector_type(4)));

#define FENCE8(a) asm volatile("" \
    : "+v"(a[0]), "+v"(a[1]), "+v"(a[2]), "+v"(a[3]), \
      "+v"(a[4]), "+v"(a[5]), "+v"(a[6]), "+v"(a[7]))

__global__ __launch_bounds__(256) void shortconv_silu_kernel(
    const float* __restrict__ x,
    const float* __restrict__ w,
    float* __restrict__ out)
{
    const int tid  = threadIdx.x;            // 0..255
    const int half = blockIdx.x & 1;         // D half
    const int s    = blockIdx.x >> 1;
    const int b    = s >> 7;                 // / NCH (=128)
    const int ci   = s & (NCH - 1);
    const int t0   = ci * STRIP;
    const int col0 = half * 1024 + tid * 4;

    const float* xp = x   + ((size_t)b * T_DIM + t0) * D_DIM + col0;
    float*       op = out + ((size_t)b * T_DIM + t0) * D_DIM + col0;

    // Per-thread weights: 4 channels x 4 taps ((D,K) row-major, 16 floats)
    const f4_t q0 = *(const f4_t*)(w + (size_t)(col0 + 0) * K_DIM);
    const f4_t q1 = *(const f4_t*)(w + (size_t)(col0 + 1) * K_DIM);
    const f4_t q2 = *(const f4_t*)(w + (size_t)(col0 + 2) * K_DIM);
    const f4_t q3 = *(const f4_t*)(w + (size_t)(col0 + 3) * K_DIM);

    // Halo window: rows t0-3..t0-1 (zeros for the first strip)
    f4_t w0, w1, w2;
    if (ci == 0) {
        w0 = (f4_t)0.f; w1 = (f4_t)0.f; w2 = (f4_t)0.f;
    } else {
        w0 = *(const f4_t*)(xp - 3 * D_DIM);
        w1 = *(const f4_t*)(xp - 2 * D_DIM);
        w2 = *(const f4_t*)(xp - 1 * D_DIM);
    }

    // Batch 0: rows t0..t0+7
    f4_t r[U];
#pragma unroll
    for (int i = 0; i < U; ++i)
        r[i] = *(const f4_t*)(xp + (size_t)i * D_DIM);

    // Fence: halo + batch0 must all be materialized here -> 11 loads
    // in flight, one graduated wait.
    asm volatile("" : "+v"(w0), "+v"(w1), "+v"(w2),
                      "+v"(r[0]), "+v"(r[1]), "+v"(r[2]), "+v"(r[3]),
                      "+v"(r[4]), "+v"(r[5]), "+v"(r[6]), "+v"(r[7]));

#pragma unroll
    for (int k = 0; k < STRIP / U; ++k) {
        // Issue next batch (rows (k+1)*U ..) before computing this one.
        f4_t n[U];
        if (k < STRIP / U - 1) {
#pragma unroll
            for (int i = 0; i < U; ++i)
                n[i] = *(const f4_t*)(xp + (size_t)((k + 1) * U + i) * D_DIM);
        }

        // Compute + store 8 rows from the fenced batch.
        f4_t a0 = w0, a1 = w1, a2 = w2;
#pragma unroll
        for (int i = 0; i < U; ++i) {
            const f4_t cur = r[i];
            f4_t y;
            y.x = q0.x * a0.x + q0.y * a1.x + q0.z * a2.x + q0.w * cur.x;
            y.y = q1.x * a0.y + q1.y * a1.y + q1.z * a2.y + q1.w * cur.y;
            y.z = q2.x * a0.z + q2.y * a1.z + q2.z * a2.z + q2.w * cur.z;
            y.w = q3.x * a0.w + q3.y * a1.w + q3.z * a2.w + q3.w * cur.w;

            // SiLU: y / (1 + exp(-y))
            y.x = y.x / (1.f + __expf(-y.x));
            y.y = y.y / (1.f + __expf(-y.y));
            y.z = y.z / (1.f + __expf(-y.z));
            y.w = y.w / (1.f + __expf(-y.w));

            *(f4_t*)(op + (size_t)(k * U + i) * D_DIM) = y;

            a0 = a1; a1 = a2; a2 = cur;
        }
        w0 = a0; w1 = a1; w2 = a2;

        if (k < STRIP / U - 1) {
            FENCE8(n);
#pragma unroll
            for (int i = 0; i < U; ++i) r[i] = n[i];
        }
    }
}

extern "C" void kernel_launch(void* const* d_in, const int* in_sizes, int n_in,
                              void* d_out, int out_size, void* d_ws, size_t ws_size,
                              hipStream_t stream) {
    const float* x = (const float*)d_in[0];
    const float* w = (const float*)d_in[1];
    float* out = (float*)d_out;

    dim3 grid(B_DIM * 2 * NCH);     // 1024 blocks (b x D-half x T-strip)
    dim3 block(256);
    shortconv_silu_kernel<<<grid, block, 0, stream>>>(x, w, out);
}